// Round 11
// baseline (439.127 us; speedup 1.0000x reference)
//
#include <hip/hip_runtime.h>
#include <hip/hip_fp16.h>
#include <math.h>

#define N_NODES 100000
#define N_EDGES 1600000
#define HDIM    128
#define NCLS    10
#define NGRAPH  1000
#define GEMM_BLOCKS  ((N_NODES + 127) / 128)   // 782
// radix-bucket CSR build
#define BSHIFT   9
#define BUCKW    (1 << BSHIFT)                 // 512 nodes / bucket
#define NB       ((N_NODES + BUCKW - 1) >> BSHIFT)   // 196
#define EPB      8192                          // edges per chunk block
#define NCHUNKS  ((N_EDGES + EPB - 1) / EPB)   // 196

typedef _Float16 half8 __attribute__((ext_vector_type(8)));
typedef _Float16 half4 __attribute__((ext_vector_type(4)));
typedef float    f32x4 __attribute__((ext_vector_type(4)));

static __device__ __forceinline__ float elu1(float x) {
  return x > 0.f ? x : (__expf(x) - 1.f);
}

// ---------- one-time W swizzle: f32 [128][128] -> fp16 B-fragment order ----
// Fragment layout (verified m89): B[n=lane&15][k=k0*32+(lane>>4)*8+j].
// Identical for every GEMM block -> hoisted out (R10: per-block transpose
// staging was 64 uncoalesced scalar loads + 64 cvt per thread per block).
__global__ __launch_bounds__(256)
void swizzle_w(const float* __restrict__ W0, const float* __restrict__ W1,
               const float* __restrict__ W2, half8* __restrict__ Wswz) {
  int f = blockIdx.x * 256 + threadIdx.x;   // 0..6143
  int which = f >> 11;
  const float* W = (which == 0) ? W0 : ((which == 1) ? W1 : W2);
  int r = f & 2047;
  int frag = r >> 6;                // k0*8+nt
  int lane = r & 63;
  int k0 = frag >> 3, nt = frag & 7;
  int n = nt * 16 + (lane & 15);
  int kbase = k0 * 32 + (lane >> 4) * 8;
  half8 hb;
#pragma unroll
  for (int j = 0; j < 8; ++j) hb[j] = (_Float16)W[(kbase + j) * 128 + n];
  Wswz[f] = hb;
}

// ---------- MFMA GEMM: Ch[n,128](fp16) = A[n,128] @ Wswz ----------
// v_mfma_f32_16x16x32_f16; block = 4 waves x 32 rows. Staging is a coalesced
// b128 copy of the pre-swizzled 32 KB W. Layouts (m89/m120):
// A[m=lane&15][k=quad*8+j], D col=lane&15 row=quad*4+reg.
template <bool AHALF>
__device__ __forceinline__
void gemm_mfma_body(const void* __restrict__ Av, const half8* __restrict__ Wswz,
                    __half* __restrict__ Ch, int nrows, half8* WtF, int bid) {
  int tid = threadIdx.x;
  for (int i = tid; i < 2048; i += 256) WtF[i] = Wswz[i];
  __syncthreads();

  int wv = tid >> 6, lane = tid & 63;
  int quad = lane >> 4, l15 = lane & 15;
  int m0 = bid * 128 + wv * 32;
  int r0 = m0 + l15;      if (r0 > nrows - 1) r0 = nrows - 1;  // clamp; stores guarded
  int r1 = m0 + 16 + l15; if (r1 > nrows - 1) r1 = nrows - 1;

  f32x4 acc[2][8];
#pragma unroll
  for (int mt = 0; mt < 2; ++mt)
#pragma unroll
    for (int nt = 0; nt < 8; ++nt) acc[mt][nt] = (f32x4){0.f, 0.f, 0.f, 0.f};

#pragma unroll
  for (int k0 = 0; k0 < 4; ++k0) {
    int koff = k0 * 32 + quad * 8;
    half8 a0, a1;
    if constexpr (AHALF) {
      const __half* Ah = (const __half*)Av;
      a0 = *(const half8*)(Ah + (size_t)r0 * 128 + koff);
      a1 = *(const half8*)(Ah + (size_t)r1 * 128 + koff);
    } else {
      const float* p0 = (const float*)Av + (size_t)r0 * 128 + koff;
      const float* p1 = (const float*)Av + (size_t)r1 * 128 + koff;
      float4 x0 = *(const float4*)p0, y0 = *(const float4*)(p0 + 4);
      float4 x1 = *(const float4*)p1, y1 = *(const float4*)(p1 + 4);
      a0[0] = (_Float16)x0.x; a0[1] = (_Float16)x0.y;
      a0[2] = (_Float16)x0.z; a0[3] = (_Float16)x0.w;
      a0[4] = (_Float16)y0.x; a0[5] = (_Float16)y0.y;
      a0[6] = (_Float16)y0.z; a0[7] = (_Float16)y0.w;
      a1[0] = (_Float16)x1.x; a1[1] = (_Float16)x1.y;
      a1[2] = (_Float16)x1.z; a1[3] = (_Float16)x1.w;
      a1[4] = (_Float16)y1.x; a1[5] = (_Float16)y1.y;
      a1[6] = (_Float16)y1.z; a1[7] = (_Float16)y1.w;
    }
#pragma unroll
    for (int nt = 0; nt < 8; ++nt) {
      half8 b = WtF[(k0 * 8 + nt) * 64 + lane];
      acc[0][nt] = __builtin_amdgcn_mfma_f32_16x16x32_f16(a0, b, acc[0][nt], 0, 0, 0);
      acc[1][nt] = __builtin_amdgcn_mfma_f32_16x16x32_f16(a1, b, acc[1][nt], 0, 0, 0);
    }
  }

#pragma unroll
  for (int mt = 0; mt < 2; ++mt) {
#pragma unroll
    for (int r = 0; r < 4; ++r) {
      int row = m0 + mt * 16 + quad * 4 + r;
      if (row < nrows) {
#pragma unroll
        for (int nt = 0; nt < 8; ++nt) {
          Ch[(size_t)row * 128 + nt * 16 + l15] = __float2half(acc[mt][nt][r]);
        }
      }
    }
  }
}

__global__ __launch_bounds__(256)
void gemm_mfma_f(const float* __restrict__ A, const half8* __restrict__ Wswz,
                 __half* __restrict__ Ch, int nrows) {
  __shared__ half8 WtF[2048];  // 32 KB
  gemm_mfma_body<false>(A, Wswz, Ch, nrows, WtF, blockIdx.x);
}

__global__ __launch_bounds__(256)
void gemm_mfma_h(const __half* __restrict__ A, const half8* __restrict__ Wswz,
                 __half* __restrict__ Ch, int nrows) {
  __shared__ half8 WtF[2048];  // 32 KB
  gemm_mfma_body<true>(A, Wswz, Ch, nrows, WtF, blockIdx.x);
}

// ---------- atomic-free CSR build (radix bucket by dst>>9) ----------
// (R9 WIN: LDS-atomic bucket pipeline, no global atomics on the hot path.)

__global__ __launch_bounds__(256)
void bucket_count(const int* __restrict__ ei, int* __restrict__ cbc) {
  __shared__ int hist[NB];
  int t = threadIdx.x;
  int c = blockIdx.x;
  if (t < NB) hist[t] = 0;
  __syncthreads();
#pragma unroll
  for (int k = 0; k < EPB / 256; ++k) {
    int e = c * EPB + k * 256 + t;
    if (e < N_EDGES) atomicAdd(&hist[ei[N_EDGES + e] >> BSHIFT], 1);
  }
  __syncthreads();
  if (t < NB) cbc[c * NB + t] = hist[t];
}

__global__ __launch_bounds__(256)
void bucket_scan(int* __restrict__ cbc, int* __restrict__ bbase) {
  int t = threadIdx.x;
  int total = 0;
  if (t < NB) {
    for (int c = 0; c < NCHUNKS; ++c) {
      int v = cbc[c * NB + t];
      cbc[c * NB + t] = total;
      total += v;
    }
  }
  __shared__ int s[256];
  s[t] = (t < NB) ? total : 0;
  __syncthreads();
#pragma unroll
  for (int d = 1; d < 256; d <<= 1) {
    int val = (t >= d) ? s[t - d] : 0;
    __syncthreads();
    s[t] += val;
    __syncthreads();
  }
  int excl = s[t] - ((t < NB) ? total : 0);
  if (t < NB) {
    bbase[t] = excl;
    if (t == NB - 1) bbase[NB] = excl + total;  // == N_EDGES
    for (int c = 0; c < NCHUNKS; ++c) cbc[c * NB + t] += excl;
  }
}

__global__ __launch_bounds__(256)
void bucket_scatter(const int* __restrict__ ei, const int* __restrict__ cbc,
                    int2* __restrict__ ebuf) {
  __shared__ int cur[NB];
  int t = threadIdx.x;
  int c = blockIdx.x;
  if (t < NB) cur[t] = cbc[c * NB + t];
  __syncthreads();
#pragma unroll
  for (int k = 0; k < EPB / 256; ++k) {
    int e = c * EPB + k * 256 + t;
    if (e < N_EDGES) {
      int s = ei[e];
      int d = ei[N_EDGES + e];
      int p = atomicAdd(&cur[d >> BSHIFT], 1);
      ebuf[p] = make_int2(s, d);
    }
  }
}

__global__ __launch_bounds__(256)
void bucket_csr(const int2* __restrict__ ebuf, const int* __restrict__ bbase,
                int* __restrict__ off, float* __restrict__ dinv,
                int* __restrict__ csrc) {
  __shared__ int hist[BUCKW];
  __shared__ int cur[BUCKW];
  __shared__ int s[256];
  int t = threadIdx.x;
  int b = blockIdx.x;
  int node0 = b << BSHIFT;
  int ebeg = bbase[b], eend = bbase[b + 1];

  hist[t] = 0; hist[t + 256] = 0;
  __syncthreads();
  for (int e = ebeg + t; e < eend; e += 256)
    atomicAdd(&hist[ebuf[e].y - node0], 1);
  __syncthreads();

  int a = hist[2 * t], bq = hist[2 * t + 1];
  int sum = a + bq;
  s[t] = sum;
  __syncthreads();
#pragma unroll
  for (int d = 1; d < 256; d <<= 1) {
    int val = (t >= d) ? s[t - d] : 0;
    __syncthreads();
    s[t] += val;
    __syncthreads();
  }
  int run = s[t] - sum;
  cur[2 * t] = run;
  cur[2 * t + 1] = run + a;

  int i0 = node0 + 2 * t, i1 = node0 + 2 * t + 1;
  if (i0 < N_NODES) {
    off[i0] = ebeg + run;
    dinv[i0] = rsqrtf((float)(a + 1));
  }
  if (i1 < N_NODES) {
    off[i1] = ebeg + run + a;
    dinv[i1] = rsqrtf((float)(bq + 1));
  }
  if (b == NB - 1 && t == 0) off[N_NODES] = N_EDGES;
  __syncthreads();

  for (int e = ebeg + t; e < eend; e += 256) {
    int2 ed = ebuf[e];
    int p = atomicAdd(&cur[ed.y - node0], 1);
    csrc[ebeg + p] = ed.x;
  }
}

// ---------- graph (pooling) ranges from SORTED batch — no atomics ----------
__global__ void gbound(const int* __restrict__ batch, int* __restrict__ goff) {
  int i = blockIdx.x * blockDim.x + threadIdx.x;
  if (i >= N_NODES) return;
  int b = batch[i];
  if (i == 0) {
    for (int g = 0; g <= b; ++g) goff[g] = 0;
  } else {
    int a = batch[i - 1];
    for (int g = a + 1; g <= b; ++g) goff[g] = i;
  }
  if (i == N_NODES - 1) {
    for (int g = b + 1; g <= NGRAPH; ++g) goff[g] = N_NODES;
  }
}

// ---------- aggregation: pairwise lanes ----------
// R10: 66.4 us vs ~48.5 us fabric floor -> issue-bound gap. New shape:
// lane owns half4 (8 B); lanes 0-31 = even edge of a pair, 32-63 = odd.
// One global_load_dwordx2 covers TWO 256 B rows -> VMEM instructions per
// edge halve. Cross-half combine via 4x shfl_xor(.,32) at the end.
__global__ __launch_bounds__(256)
void aggregate(const __half* __restrict__ h, const int* __restrict__ off,
               const int* __restrict__ csrc, const float* __restrict__ dinv,
               const float* __restrict__ bias, __half* __restrict__ out) {
  int gid = blockIdx.x * blockDim.x + threadIdx.x;
  int node = gid >> 6;
  int lane = gid & 63;
  if (node >= N_NODES) return;
  int hf = lane >> 5;        // pair half
  int l32 = lane & 31;       // features 4*l32 .. 4*l32+3
  const __half* hb = h + (size_t)l32 * 4;

  int beg = off[node], end = off[node + 1];
  int deg = end - beg;
  int npair = deg >> 1;
  int base = beg + hf;

  float A0 = 0.f, A1 = 0.f, A2 = 0.f, A3 = 0.f;
  float B0 = 0.f, B1 = 0.f, B2 = 0.f, B3 = 0.f;

  int p = 0;
  for (; p + 4 <= npair; p += 4) {
    int e0 = base + 2 * p;
    int s0 = csrc[e0], s1 = csrc[e0 + 2], s2 = csrc[e0 + 4], s3 = csrc[e0 + 6];
    float w0 = dinv[s0], w1 = dinv[s1], w2 = dinv[s2], w3 = dinv[s3];
    half4 v0 = *(const half4*)(hb + (size_t)s0 * 128);
    half4 v1 = *(const half4*)(hb + (size_t)s1 * 128);
    half4 v2 = *(const half4*)(hb + (size_t)s2 * 128);
    half4 v3 = *(const half4*)(hb + (size_t)s3 * 128);
    A0 = fmaf(w0, (float)v0[0], A0); A1 = fmaf(w0, (float)v0[1], A1);
    A2 = fmaf(w0, (float)v0[2], A2); A3 = fmaf(w0, (float)v0[3], A3);
    B0 = fmaf(w1, (float)v1[0], B0); B1 = fmaf(w1, (float)v1[1], B1);
    B2 = fmaf(w1, (float)v1[2], B2); B3 = fmaf(w1, (float)v1[3], B3);
    A0 = fmaf(w2, (float)v2[0], A0); A1 = fmaf(w2, (float)v2[1], A1);
    A2 = fmaf(w2, (float)v2[2], A2); A3 = fmaf(w2, (float)v2[3], A3);
    B0 = fmaf(w3, (float)v3[0], B0); B1 = fmaf(w3, (float)v3[1], B1);
    B2 = fmaf(w3, (float)v3[2], B2); B3 = fmaf(w3, (float)v3[3], B3);
  }
  if (p + 2 <= npair) {
    int e0 = base + 2 * p;
    int s0 = csrc[e0], s1 = csrc[e0 + 2];
    float w0 = dinv[s0], w1 = dinv[s1];
    half4 v0 = *(const half4*)(hb + (size_t)s0 * 128);
    half4 v1 = *(const half4*)(hb + (size_t)s1 * 128);
    A0 = fmaf(w0, (float)v0[0], A0); A1 = fmaf(w0, (float)v0[1], A1);
    A2 = fmaf(w0, (float)v0[2], A2); A3 = fmaf(w0, (float)v0[3], A3);
    B0 = fmaf(w1, (float)v1[0], B0); B1 = fmaf(w1, (float)v1[1], B1);
    B2 = fmaf(w1, (float)v1[2], B2); B3 = fmaf(w1, (float)v1[3], B3);
    p += 2;
  }
  if (p < npair) {
    int e0 = base + 2 * p;
    int s0 = csrc[e0];
    float w0 = dinv[s0];
    half4 v0 = *(const half4*)(hb + (size_t)s0 * 128);
    A0 = fmaf(w0, (float)v0[0], A0); A1 = fmaf(w0, (float)v0[1], A1);
    A2 = fmaf(w0, (float)v0[2], A2); A3 = fmaf(w0, (float)v0[3], A3);
  }
  if ((deg & 1) && hf == 0) {   // odd tail: even-half lanes only
    int s0 = csrc[end - 1];
    float w0 = dinv[s0];
    half4 v0 = *(const half4*)(hb + (size_t)s0 * 128);
    A0 = fmaf(w0, (float)v0[0], A0); A1 = fmaf(w0, (float)v0[1], A1);
    A2 = fmaf(w0, (float)v0[2], A2); A3 = fmaf(w0, (float)v0[3], A3);
  }

  A0 += B0; A1 += B1; A2 += B2; A3 += B3;
  A0 += __shfl_xor(A0, 32); A1 += __shfl_xor(A1, 32);
  A2 += __shfl_xor(A2, 32); A3 += __shfl_xor(A3, 32);

  if (hf == 0) {
    float dv = dinv[node];
    half4 vs = *(const half4*)(hb + (size_t)node * 128);
    A0 = fmaf(dv, (float)vs[0], A0); A1 = fmaf(dv, (float)vs[1], A1);
    A2 = fmaf(dv, (float)vs[2], A2); A3 = fmaf(dv, (float)vs[3], A3);
    float4 bb = ((const float4*)bias)[l32];
    half4 o;
    o[0] = (_Float16)elu1(fmaf(dv, A0, bb.x));
    o[1] = (_Float16)elu1(fmaf(dv, A1, bb.y));
    o[2] = (_Float16)elu1(fmaf(dv, A2, bb.z));
    o[3] = (_Float16)elu1(fmaf(dv, A3, bb.w));
    *(half4*)(out + (size_t)node * 128 + l32 * 4) = o;
  }
}

// ---------- fused max-pool + linear head + softmax ----------
__global__ void pool_head(const __half* __restrict__ feat, const int* __restrict__ goff,
                          const float* __restrict__ Wl, const float* __restrict__ bl,
                          float* __restrict__ out) {
  int g = blockIdx.x;
  int t = threadIdx.x;
  int beg = goff[g], end = goff[g + 1];

  float m0 = -INFINITY, m1 = -INFINITY, m2 = -INFINITY, m3 = -INFINITY;
  int i = beg;
  for (; i + 4 <= end; i += 4) {
    m0 = fmaxf(m0, __half2float(feat[(size_t)(i + 0) * HDIM + t]));
    m1 = fmaxf(m1, __half2float(feat[(size_t)(i + 1) * HDIM + t]));
    m2 = fmaxf(m2, __half2float(feat[(size_t)(i + 2) * HDIM + t]));
    m3 = fmaxf(m3, __half2float(feat[(size_t)(i + 3) * HDIM + t]));
  }
  for (; i < end; ++i) m0 = fmaxf(m0, __half2float(feat[(size_t)i * HDIM + t]));
  float m = fmaxf(fmaxf(m0, m1), fmaxf(m2, m3));
  if (beg == end) m = 0.f;

  __shared__ float pl[HDIM];
  __shared__ float lg[NCLS];
  pl[t] = m;
  __syncthreads();

  if (t < NCLS) {
    float acc = bl[t];
#pragma unroll
    for (int f = 0; f < HDIM; ++f) acc = fmaf(pl[f], Wl[f * NCLS + t], acc);
    lg[t] = acc;
  }
  __syncthreads();

  if (t < NCLS) {
    float mx = lg[0];
#pragma unroll
    for (int c = 1; c < NCLS; ++c) mx = fmaxf(mx, lg[c]);
    float ssum = 0.f;
#pragma unroll
    for (int c = 0; c < NCLS; ++c) ssum += __expf(lg[c] - mx);
    out[g * NCLS + t] = __expf(lg[t] - mx) / ssum;
  }
}

// ---------- launch ----------

extern "C" void kernel_launch(void* const* d_in, const int* in_sizes, int n_in,
                              void* d_out, int out_size, void* d_ws, size_t ws_size,
                              hipStream_t stream) {
  const float* x    = (const float*)d_in[0];
  const int*   ei   = (const int*)d_in[1];
  const int*   batch= (const int*)d_in[2];
  const float* W0 = (const float*)d_in[3]; const float* b0 = (const float*)d_in[4];
  const float* W1 = (const float*)d_in[5]; const float* b1 = (const float*)d_in[6];
  const float* W2 = (const float*)d_in[7]; const float* b2 = (const float*)d_in[8];
  const float* Wl = (const float*)d_in[9]; const float* bl = (const float*)d_in[10];
  float* out = (float*)d_out;

  char* w = (char*)d_ws;
  auto alloc = [&](size_t bytes) {
    char* p = w;
    w += (bytes + 255) & ~(size_t)255;
    return p;
  };
  int*    cbc    = (int*)   alloc((size_t)NCHUNKS * NB * 4);
  int*    bbase  = (int*)   alloc((size_t)(NB + 1) * 4);
  int2*   ebuf   = (int2*)  alloc((size_t)N_EDGES * 8);
  int*    off    = (int*)   alloc((size_t)(N_NODES + 1) * 4);
  float*  dinv   = (float*) alloc((size_t)N_NODES * 4);
  int*    goff   = (int*)   alloc((size_t)(NGRAPH + 1) * 4);
  int*    csrc   = (int*)   alloc((size_t)N_EDGES * 4);
  half8*  Wswz   = (half8*) alloc((size_t)3 * 2048 * 16);
  __half* hbuf   = (__half*)alloc((size_t)N_NODES * HDIM * 2);
  __half* feat   = (__half*)alloc((size_t)N_NODES * HDIM * 2);

  // one-time W swizzle (all 3 layers)
  swizzle_w<<<24, 256, 0, stream>>>(W0, W1, W2, Wswz);

  // layer-0 GEMM (MFMA)
  gemm_mfma_f<<<GEMM_BLOCKS, 256, 0, stream>>>(x, Wswz, hbuf, N_NODES);

  // atomic-free CSR build
  bucket_count<<<NCHUNKS, 256, 0, stream>>>(ei, cbc);
  bucket_scan<<<1, 256, 0, stream>>>(cbc, bbase);
  bucket_scatter<<<NCHUNKS, 256, 0, stream>>>(ei, cbc, ebuf);
  bucket_csr<<<NB, 256, 0, stream>>>(ebuf, bbase, off, dinv, csrc);

  gbound<<<(N_NODES + 255) / 256, 256, 0, stream>>>(batch, goff);

  aggregate<<<((size_t)N_NODES * 64 + 255) / 256, 256, 0, stream>>>(
      hbuf, off, csrc, dinv, b0, feat);

  gemm_mfma_h<<<GEMM_BLOCKS, 256, 0, stream>>>(feat, Wswz + 2048, hbuf, N_NODES);
  aggregate<<<((size_t)N_NODES * 64 + 255) / 256, 256, 0, stream>>>(
      hbuf, off, csrc, dinv, b1, feat);

  gemm_mfma_h<<<GEMM_BLOCKS, 256, 0, stream>>>(feat, Wswz + 4096, hbuf, N_NODES);
  aggregate<<<((size_t)N_NODES * 64 + 255) / 256, 256, 0, stream>>>(
      hbuf, off, csrc, dinv, b2, feat);

  pool_head<<<NGRAPH, 128, 0, stream>>>(feat, goff, Wl, bl, out);
}

// Round 12
// 410.827 us; speedup vs baseline: 1.0689x; 1.0689x over previous
//
#include <hip/hip_runtime.h>
#include <hip/hip_fp16.h>
#include <math.h>

#define N_NODES 100000
#define N_EDGES 1600000
#define HDIM    128
#define NCLS    10
#define NGRAPH  1000
#define GEMM_BLOCKS  ((N_NODES + 127) / 128)   // 782
// radix-bucket CSR build
#define BSHIFT   9
#define BUCKW    (1 << BSHIFT)                 // 512 nodes / bucket
#define NB       ((N_NODES + BUCKW - 1) >> BSHIFT)   // 196
#define EPB      4096                          // edges per chunk block
#define NCHUNKS  ((N_EDGES + EPB - 1) / EPB)   // 391

typedef _Float16 half8 __attribute__((ext_vector_type(8)));
typedef float    f32x4 __attribute__((ext_vector_type(4)));

static __device__ __forceinline__ float elu1(float x) {
  return x > 0.f ? x : (__expf(x) - 1.f);
}

// ---------- one-time W swizzle: f32 [128][128] -> fp16 B-fragment order ----
// B[n=lane&15][k=k0*32+(lane>>4)*8+j] (verified m89). Hoisted out of the
// GEMM blocks (R10 WIN: staging becomes a coalesced b128 copy).
__global__ __launch_bounds__(256)
void swizzle_w(const float* __restrict__ W0, const float* __restrict__ W1,
               const float* __restrict__ W2, half8* __restrict__ Wswz) {
  int f = blockIdx.x * 256 + threadIdx.x;   // 0..6143
  int which = f >> 11;
  const float* W = (which == 0) ? W0 : ((which == 1) ? W1 : W2);
  int r = f & 2047;
  int frag = r >> 6;                // k0*8+nt
  int lane = r & 63;
  int k0 = frag >> 3, nt = frag & 7;
  int n = nt * 16 + (lane & 15);
  int kbase = k0 * 32 + (lane >> 4) * 8;
  half8 hb;
#pragma unroll
  for (int j = 0; j < 8; ++j) hb[j] = (_Float16)W[(kbase + j) * 128 + n];
  Wswz[f] = hb;
}

// ---------- MFMA GEMM: Ch[n,128](fp16) = A[n,128] @ Wswz ----------
// v_mfma_f32_16x16x32_f16; block = 4 waves x 32 rows. Layouts (m89/m120):
// A[m=lane&15][k=quad*8+j], D col=lane&15 row=quad*4+reg.
template <bool AHALF>
__device__ __forceinline__
void gemm_mfma_body(const void* __restrict__ Av, const half8* __restrict__ Wswz,
                    __half* __restrict__ Ch, int nrows, half8* WtF, int bid) {
  int tid = threadIdx.x;
  for (int i = tid; i < 2048; i += 256) WtF[i] = Wswz[i];
  __syncthreads();

  int wv = tid >> 6, lane = tid & 63;
  int quad = lane >> 4, l15 = lane & 15;
  int m0 = bid * 128 + wv * 32;
  int r0 = m0 + l15;      if (r0 > nrows - 1) r0 = nrows - 1;  // clamp; stores guarded
  int r1 = m0 + 16 + l15; if (r1 > nrows - 1) r1 = nrows - 1;

  f32x4 acc[2][8];
#pragma unroll
  for (int mt = 0; mt < 2; ++mt)
#pragma unroll
    for (int nt = 0; nt < 8; ++nt) acc[mt][nt] = (f32x4){0.f, 0.f, 0.f, 0.f};

#pragma unroll
  for (int k0 = 0; k0 < 4; ++k0) {
    int koff = k0 * 32 + quad * 8;
    half8 a0, a1;
    if constexpr (AHALF) {
      const __half* Ah = (const __half*)Av;
      a0 = *(const half8*)(Ah + (size_t)r0 * 128 + koff);
      a1 = *(const half8*)(Ah + (size_t)r1 * 128 + koff);
    } else {
      const float* p0 = (const float*)Av + (size_t)r0 * 128 + koff;
      const float* p1 = (const float*)Av + (size_t)r1 * 128 + koff;
      float4 x0 = *(const float4*)p0, y0 = *(const float4*)(p0 + 4);
      float4 x1 = *(const float4*)p1, y1 = *(const float4*)(p1 + 4);
      a0[0] = (_Float16)x0.x; a0[1] = (_Float16)x0.y;
      a0[2] = (_Float16)x0.z; a0[3] = (_Float16)x0.w;
      a0[4] = (_Float16)y0.x; a0[5] = (_Float16)y0.y;
      a0[6] = (_Float16)y0.z; a0[7] = (_Float16)y0.w;
      a1[0] = (_Float16)x1.x; a1[1] = (_Float16)x1.y;
      a1[2] = (_Float16)x1.z; a1[3] = (_Float16)x1.w;
      a1[4] = (_Float16)y1.x; a1[5] = (_Float16)y1.y;
      a1[6] = (_Float16)y1.z; a1[7] = (_Float16)y1.w;
    }
#pragma unroll
    for (int nt = 0; nt < 8; ++nt) {
      half8 b = WtF[(k0 * 8 + nt) * 64 + lane];
      acc[0][nt] = __builtin_amdgcn_mfma_f32_16x16x32_f16(a0, b, acc[0][nt], 0, 0, 0);
      acc[1][nt] = __builtin_amdgcn_mfma_f32_16x16x32_f16(a1, b, acc[1][nt], 0, 0, 0);
    }
  }

#pragma unroll
  for (int mt = 0; mt < 2; ++mt) {
#pragma unroll
    for (int r = 0; r < 4; ++r) {
      int row = m0 + mt * 16 + quad * 4 + r;
      if (row < nrows) {
#pragma unroll
        for (int nt = 0; nt < 8; ++nt) {
          Ch[(size_t)row * 128 + nt * 16 + l15] = __float2half(acc[mt][nt][r]);
        }
      }
    }
  }
}

__global__ __launch_bounds__(256)
void gemm_mfma_f(const float* __restrict__ A, const half8* __restrict__ Wswz,
                 __half* __restrict__ Ch, int nrows) {
  __shared__ half8 WtF[2048];  // 32 KB
  gemm_mfma_body<false>(A, Wswz, Ch, nrows, WtF, blockIdx.x);
}

__global__ __launch_bounds__(256)
void gemm_mfma_h(const __half* __restrict__ A, const half8* __restrict__ Wswz,
                 __half* __restrict__ Ch, int nrows) {
  __shared__ half8 WtF[2048];  // 32 KB
  gemm_mfma_body<true>(A, Wswz, Ch, nrows, WtF, blockIdx.x);
}

// ---------- atomic-free CSR build (radix bucket by dst>>9) ----------
// R9 WIN (LDS atomics only). R11 post-mortem: old bucket_scan was ONE block
// with two 391-long serial load/store chains per thread -> parallelized into
// scan_chunks (one block per bucket) + scan_base; base-add folded into the
// scatter. Scatter now stages edges in LDS and flushes per-bucket segments
// coalesced (old version: ~50 scattered 8 B transactions per wave).

// A: per-chunk histogram over 196 buckets -> cbc[chunk][bucket] (counts)
__global__ __launch_bounds__(256)
void bucket_count(const int* __restrict__ ei, int* __restrict__ cbc) {
  __shared__ int hist[NB];
  int t = threadIdx.x;
  int c = blockIdx.x;
  if (t < NB) hist[t] = 0;
  __syncthreads();
#pragma unroll
  for (int k = 0; k < EPB / 256; ++k) {
    int e = c * EPB + k * 256 + t;
    if (e < N_EDGES) atomicAdd(&hist[ei[N_EDGES + e] >> BSHIFT], 1);
  }
  __syncthreads();
  if (t < NB) cbc[c * NB + t] = hist[t];
}

// B1: per-bucket exclusive scan along the chunk axis (parallel over buckets)
__global__ __launch_bounds__(256)
void scan_chunks(const int* __restrict__ cbc, int* __restrict__ cpre,
                 int* __restrict__ btot) {
  __shared__ int s[256];
  int b = blockIdx.x;
  int t = threadIdx.x;
  int c0 = 2 * t, c1 = 2 * t + 1;
  int v0 = (c0 < NCHUNKS) ? cbc[c0 * NB + b] : 0;
  int v1 = (c1 < NCHUNKS) ? cbc[c1 * NB + b] : 0;
  int sum = v0 + v1;
  s[t] = sum;
  __syncthreads();
#pragma unroll
  for (int d = 1; d < 256; d <<= 1) {
    int val = (t >= d) ? s[t - d] : 0;
    __syncthreads();
    s[t] += val;
    __syncthreads();
  }
  int run = s[t] - sum;
  if (c0 < NCHUNKS) cpre[c0 * NB + b] = run;
  if (c1 < NCHUNKS) cpre[c1 * NB + b] = run + v0;
  if (t == 255) btot[b] = s[255];
}

// B2: exclusive scan over bucket totals -> bbase[b], bbase[NB] = E
__global__ __launch_bounds__(256)
void scan_base(const int* __restrict__ btot, int* __restrict__ bbase) {
  __shared__ int s[256];
  int t = threadIdx.x;
  int v = (t < NB) ? btot[t] : 0;
  s[t] = v;
  __syncthreads();
#pragma unroll
  for (int d = 1; d < 256; d <<= 1) {
    int val = (t >= d) ? s[t - d] : 0;
    __syncthreads();
    s[t] += val;
    __syncthreads();
  }
  if (t < NB) bbase[t] = s[t] - v;
  if (t == 255) bbase[NB] = s[255];  // == N_EDGES
}

// C: scatter edges bucket-ordered via a 32 KB LDS stage; flush per-bucket
// segments with coalesced lane-consecutive writes.
__global__ __launch_bounds__(256)
void bucket_scatter(const int* __restrict__ ei, const int* __restrict__ cbc,
                    const int* __restrict__ cpre, const int* __restrict__ bbase,
                    int2* __restrict__ ebuf) {
  __shared__ int lb[NB + 1];
  __shared__ int lcur[NB];
  __shared__ int s[256];
  __shared__ int2 stage[EPB];  // 32 KB
  int t = threadIdx.x;
  int c = blockIdx.x;

  // local exclusive scan of this chunk's bucket counts
  int v = (t < NB) ? cbc[c * NB + t] : 0;
  s[t] = v;
  __syncthreads();
#pragma unroll
  for (int d = 1; d < 256; d <<= 1) {
    int val = (t >= d) ? s[t - d] : 0;
    __syncthreads();
    s[t] += val;
    __syncthreads();
  }
  if (t < NB) {
    int excl = s[t] - v;
    lb[t] = excl;
    lcur[t] = excl;
  }
  if (t == 255) lb[NB] = s[255];  // edges in this chunk
  __syncthreads();

  // scatter into LDS (bucket-grouped)
#pragma unroll
  for (int k = 0; k < EPB / 256; ++k) {
    int e = c * EPB + k * 256 + t;
    if (e < N_EDGES) {
      int src = ei[e];
      int d = ei[N_EDGES + e];
      int p = atomicAdd(&lcur[d >> BSHIFT], 1);
      stage[p] = make_int2(src, d);
    }
  }
  __syncthreads();

  // coalesced flush: wave w handles buckets w, w+4, ...
  int wv = t >> 6, lane = t & 63;
  for (int b = wv; b < NB; b += 4) {
    int l0 = lb[b], l1 = lb[b + 1];
    int gb = bbase[b] + cpre[c * NB + b];
    for (int i = lane; i < l1 - l0; i += 64) ebuf[gb + i] = stage[l0 + i];
  }
}

// D: one block per bucket: LDS 512-histogram + local scan -> off, dinv,
// and dst-sorted csrc.
__global__ __launch_bounds__(256)
void bucket_csr(const int2* __restrict__ ebuf, const int* __restrict__ bbase,
                int* __restrict__ off, float* __restrict__ dinv,
                int* __restrict__ csrc) {
  __shared__ int hist[BUCKW];
  __shared__ int cur[BUCKW];
  __shared__ int s[256];
  int t = threadIdx.x;
  int b = blockIdx.x;
  int node0 = b << BSHIFT;
  int ebeg = bbase[b], eend = bbase[b + 1];

  hist[t] = 0; hist[t + 256] = 0;
  __syncthreads();
  for (int e = ebeg + t; e < eend; e += 256)
    atomicAdd(&hist[ebuf[e].y - node0], 1);
  __syncthreads();

  int a = hist[2 * t], bq = hist[2 * t + 1];
  int sum = a + bq;
  s[t] = sum;
  __syncthreads();
#pragma unroll
  for (int d = 1; d < 256; d <<= 1) {
    int val = (t >= d) ? s[t - d] : 0;
    __syncthreads();
    s[t] += val;
    __syncthreads();
  }
  int run = s[t] - sum;
  cur[2 * t] = run;
  cur[2 * t + 1] = run + a;

  int i0 = node0 + 2 * t, i1 = node0 + 2 * t + 1;
  if (i0 < N_NODES) {
    off[i0] = ebeg + run;
    dinv[i0] = rsqrtf((float)(a + 1));
  }
  if (i1 < N_NODES) {
    off[i1] = ebeg + run + a;
    dinv[i1] = rsqrtf((float)(bq + 1));
  }
  if (b == NB - 1 && t == 0) off[N_NODES] = N_EDGES;
  __syncthreads();

  for (int e = ebeg + t; e < eend; e += 256) {
    int2 ed = ebuf[e];
    int p = atomicAdd(&cur[ed.y - node0], 1);
    csrc[ebeg + p] = ed.x;
  }
}

// ---------- graph (pooling) ranges from SORTED batch — no atomics ----------
__global__ void gbound(const int* __restrict__ batch, int* __restrict__ goff) {
  int i = blockIdx.x * blockDim.x + threadIdx.x;
  if (i >= N_NODES) return;
  int b = batch[i];
  if (i == 0) {
    for (int g = 0; g <= b; ++g) goff[g] = 0;
  } else {
    int a = batch[i - 1];
    for (int g = a + 1; g <= b; ++g) goff[g] = i;
  }
  if (i == N_NODES - 1) {
    for (int g = b + 1; g <= NGRAPH; ++g) goff[g] = N_NODES;
  }
}

// ---------- aggregation (R10's best: wave/node, half2/lane, 8-deep MLP) ----
// R11 post-mortem: pairwise-lane shape was neutral-negative; this shape's
// ~66 us is the cache-hierarchy service floor (FETCH pinned at 194 MB).
__global__ __launch_bounds__(256)
void aggregate(const __half* __restrict__ h, const int* __restrict__ off,
               const int* __restrict__ csrc, const float* __restrict__ dinv,
               const float* __restrict__ bias, __half* __restrict__ out) {
  int gid = blockIdx.x * blockDim.x + threadIdx.x;
  int node = gid >> 6;
  int lane = gid & 63;
  if (node >= N_NODES) return;
  const __half2* h2 = (const __half2*)h;

  int beg = off[node], end = off[node + 1];
  float a0 = 0.f, a1 = 0.f;
  float b0_ = 0.f, b1_ = 0.f;
  float c0 = 0.f, c1 = 0.f;
  float d0 = 0.f, d1 = 0.f;

  int e = beg;
  for (; e + 8 <= end; e += 8) {
    int s0 = csrc[e + 0], s1 = csrc[e + 1], s2 = csrc[e + 2], s3 = csrc[e + 3];
    int s4 = csrc[e + 4], s5 = csrc[e + 5], s6 = csrc[e + 6], s7 = csrc[e + 7];
    float w0 = dinv[s0], w1 = dinv[s1], w2 = dinv[s2], w3 = dinv[s3];
    float w4 = dinv[s4], w5 = dinv[s5], w6 = dinv[s6], w7 = dinv[s7];
    float2 f0 = __half22float2(h2[(size_t)s0 * 64 + lane]);
    float2 f1 = __half22float2(h2[(size_t)s1 * 64 + lane]);
    float2 f2 = __half22float2(h2[(size_t)s2 * 64 + lane]);
    float2 f3 = __half22float2(h2[(size_t)s3 * 64 + lane]);
    float2 f4 = __half22float2(h2[(size_t)s4 * 64 + lane]);
    float2 f5 = __half22float2(h2[(size_t)s5 * 64 + lane]);
    float2 f6 = __half22float2(h2[(size_t)s6 * 64 + lane]);
    float2 f7 = __half22float2(h2[(size_t)s7 * 64 + lane]);
    a0 = fmaf(w0, f0.x, a0); a1 = fmaf(w0, f0.y, a1);
    b0_ = fmaf(w1, f1.x, b0_); b1_ = fmaf(w1, f1.y, b1_);
    c0 = fmaf(w2, f2.x, c0); c1 = fmaf(w2, f2.y, c1);
    d0 = fmaf(w3, f3.x, d0); d1 = fmaf(w3, f3.y, d1);
    a0 = fmaf(w4, f4.x, a0); a1 = fmaf(w4, f4.y, a1);
    b0_ = fmaf(w5, f5.x, b0_); b1_ = fmaf(w5, f5.y, b1_);
    c0 = fmaf(w6, f6.x, c0); c1 = fmaf(w6, f6.y, c1);
    d0 = fmaf(w7, f7.x, d0); d1 = fmaf(w7, f7.y, d1);
  }
  if (e + 4 <= end) {
    int s0 = csrc[e + 0], s1 = csrc[e + 1], s2 = csrc[e + 2], s3 = csrc[e + 3];
    float w0 = dinv[s0], w1 = dinv[s1], w2 = dinv[s2], w3 = dinv[s3];
    float2 f0 = __half22float2(h2[(size_t)s0 * 64 + lane]);
    float2 f1 = __half22float2(h2[(size_t)s1 * 64 + lane]);
    float2 f2 = __half22float2(h2[(size_t)s2 * 64 + lane]);
    float2 f3 = __half22float2(h2[(size_t)s3 * 64 + lane]);
    a0 = fmaf(w0, f0.x, a0); a1 = fmaf(w0, f0.y, a1);
    b0_ = fmaf(w1, f1.x, b0_); b1_ = fmaf(w1, f1.y, b1_);
    c0 = fmaf(w2, f2.x, c0); c1 = fmaf(w2, f2.y, c1);
    d0 = fmaf(w3, f3.x, d0); d1 = fmaf(w3, f3.y, d1);
    e += 4;
  }
  if (e + 2 <= end) {
    int s0 = csrc[e + 0], s1 = csrc[e + 1];
    float w0 = dinv[s0], w1 = dinv[s1];
    float2 f0 = __half22float2(h2[(size_t)s0 * 64 + lane]);
    float2 f1 = __half22float2(h2[(size_t)s1 * 64 + lane]);
    a0 = fmaf(w0, f0.x, a0); a1 = fmaf(w0, f0.y, a1);
    b0_ = fmaf(w1, f1.x, b0_); b1_ = fmaf(w1, f1.y, b1_);
    e += 2;
  }
  if (e < end) {
    int s0 = csrc[e];
    float w0 = dinv[s0];
    float2 f0 = __half22float2(h2[(size_t)s0 * 64 + lane]);
    a0 = fmaf(w0, f0.x, a0); a1 = fmaf(w0, f0.y, a1);
  }

  float dv = dinv[node];
  float2 vs = __half22float2(h2[(size_t)node * 64 + lane]);
  float s0f = (a0 + b0_) + (c0 + d0) + dv * vs.x;
  float s1f = (a1 + b1_) + (c1 + d1) + dv * vs.y;

  float2 bb = ((const float2*)bias)[lane];
  float ox = elu1(fmaf(dv, s0f, bb.x));
  float oy = elu1(fmaf(dv, s1f, bb.y));
  ((__half2*)out)[(size_t)node * 64 + lane] = __floats2half2_rn(ox, oy);
}

// ---------- fused max-pool + linear head + softmax ----------
__global__ void pool_head(const __half* __restrict__ feat, const int* __restrict__ goff,
                          const float* __restrict__ Wl, const float* __restrict__ bl,
                          float* __restrict__ out) {
  int g = blockIdx.x;
  int t = threadIdx.x;
  int beg = goff[g], end = goff[g + 1];

  float m0 = -INFINITY, m1 = -INFINITY, m2 = -INFINITY, m3 = -INFINITY;
  int i = beg;
  for (; i + 4 <= end; i += 4) {
    m0 = fmaxf(m0, __half2float(feat[(size_t)(i + 0) * HDIM + t]));
    m1 = fmaxf(m1, __half2float(feat[(size_t)(i + 1) * HDIM + t]));
    m2 = fmaxf(m2, __half2float(feat[(size_t)(i + 2) * HDIM + t]));
    m3 = fmaxf(m3, __half2float(feat[(size_t)(i + 3) * HDIM + t]));
  }
  for (; i < end; ++i) m0 = fmaxf(m0, __half2float(feat[(size_t)i * HDIM + t]));
  float m = fmaxf(fmaxf(m0, m1), fmaxf(m2, m3));
  if (beg == end) m = 0.f;

  __shared__ float pl[HDIM];
  __shared__ float lg[NCLS];
  pl[t] = m;
  __syncthreads();

  if (t < NCLS) {
    float acc = bl[t];
#pragma unroll
    for (int f = 0; f < HDIM; ++f) acc = fmaf(pl[f], Wl[f * NCLS + t], acc);
    lg[t] = acc;
  }
  __syncthreads();

  if (t < NCLS) {
    float mx = lg[0];
#pragma unroll
    for (int c = 1; c < NCLS; ++c) mx = fmaxf(mx, lg[c]);
    float ssum = 0.f;
#pragma unroll
    for (int c = 0; c < NCLS; ++c) ssum += __expf(lg[c] - mx);
    out[g * NCLS + t] = __expf(lg[t] - mx) / ssum;
  }
}

// ---------- launch ----------

extern "C" void kernel_launch(void* const* d_in, const int* in_sizes, int n_in,
                              void* d_out, int out_size, void* d_ws, size_t ws_size,
                              hipStream_t stream) {
  const float* x    = (const float*)d_in[0];
  const int*   ei   = (const int*)d_in[1];
  const int*   batch= (const int*)d_in[2];
  const float* W0 = (const float*)d_in[3]; const float* b0 = (const float*)d_in[4];
  const float* W1 = (const float*)d_in[5]; const float* b1 = (const float*)d_in[6];
  const float* W2 = (const float*)d_in[7]; const float* b2 = (const float*)d_in[8];
  const float* Wl = (const float*)d_in[9]; const float* bl = (const float*)d_in[10];
  float* out = (float*)d_out;

  char* w = (char*)d_ws;
  auto alloc = [&](size_t bytes) {
    char* p = w;
    w += (bytes + 255) & ~(size_t)255;
    return p;
  };
  int*    cbc    = (int*)   alloc((size_t)NCHUNKS * NB * 4);
  int*    cpre   = (int*)   alloc((size_t)NCHUNKS * NB * 4);
  int*    btot   = (int*)   alloc((size_t)NB * 4);
  int*    bbase  = (int*)   alloc((size_t)(NB + 1) * 4);
  int2*   ebuf   = (int2*)  alloc((size_t)N_EDGES * 8);
  int*    off    = (int*)   alloc((size_t)(N_NODES + 1) * 4);
  float*  dinv   = (float*) alloc((size_t)N_NODES * 4);
  int*    goff   = (int*)   alloc((size_t)(NGRAPH + 1) * 4);
  int*    csrc   = (int*)   alloc((size_t)N_EDGES * 4);
  half8*  Wswz   = (half8*) alloc((size_t)3 * 2048 * 16);
  __half* hbuf   = (__half*)alloc((size_t)N_NODES * HDIM * 2);
  __half* feat   = (__half*)alloc((size_t)N_NODES * HDIM * 2);

  // one-time W swizzle (all 3 layers)
  swizzle_w<<<24, 256, 0, stream>>>(W0, W1, W2, Wswz);

  // layer-0 GEMM (MFMA)
  gemm_mfma_f<<<GEMM_BLOCKS, 256, 0, stream>>>(x, Wswz, hbuf, N_NODES);

  // atomic-free CSR build (parallel scans, LDS-staged coalesced scatter)
  bucket_count<<<NCHUNKS, 256, 0, stream>>>(ei, cbc);
  scan_chunks<<<NB, 256, 0, stream>>>(cbc, cpre, btot);
  scan_base<<<1, 256, 0, stream>>>(btot, bbase);
  bucket_scatter<<<NCHUNKS, 256, 0, stream>>>(ei, cbc, cpre, bbase, ebuf);
  bucket_csr<<<NB, 256, 0, stream>>>(ebuf, bbase, off, dinv, csrc);

  gbound<<<(N_NODES + 255) / 256, 256, 0, stream>>>(batch, goff);

  aggregate<<<((size_t)N_NODES * 64 + 255) / 256, 256, 0, stream>>>(
      hbuf, off, csrc, dinv, b0, feat);

  gemm_mfma_h<<<GEMM_BLOCKS, 256, 0, stream>>>(feat, Wswz + 2048, hbuf, N_NODES);
  aggregate<<<((size_t)N_NODES * 64 + 255) / 256, 256, 0, stream>>>(
      hbuf, off, csrc, dinv, b1, feat);

  gemm_mfma_h<<<GEMM_BLOCKS, 256, 0, stream>>>(feat, Wswz + 4096, hbuf, N_NODES);
  aggregate<<<((size_t)N_NODES * 64 + 255) / 256, 256, 0, stream>>>(
      hbuf, off, csrc, dinv, b2, feat);

  pool_head<<<NGRAPH, 128, 0, stream>>>(feat, goff, Wl, bl, out);
}